// Round 1
// baseline (226.279 us; speedup 1.0000x reference)
//
#include <hip/hip_runtime.h>

// CapsuleLayer dynamic routing, fully fused per (k,b) pair.
//   priors P[r,o] = sum_c x[b,r,c] * w[k,r,c,o]      (R=2048, C=16, O=32)
//   u0 = sigmoid(colsum(P)/R)
//   f(v) = P^T softmax(P v);  u1 = sigmoid(f(u0));  out = sigmoid(f(u0+u1))
// One 1024-thread block per (k,b). P held on-chip: rows 0..1023 in LDS
// (XOR-swizzled float4 layout), rows 1024..2047 in registers (8 float4/thread).
// Thread t: o4 = t&7 owns output columns [4*o4, 4*o4+4); G = t>>3 owns rows
// {8G+j} (LDS) and {1024+8G+j} (regs), j=0..7.

#define KK 32
#define BB 32
#define RR 2048
#define CC 16
#define OO 32
#define THREADS 1024

#define PLDS_FLOATS (1024 * 32)
#define SWV_OFF PLDS_FLOATS            // [16][32] per-wave partials
#define SU_OFF (SWV_OFF + 16 * 32)     // [32] u-vector (u0, then u0+u1)
#define SM_OFF (SU_OFF + 32)           // [16] per-wave max
#define SZ_OFF (SM_OFF + 16)           // [16] per-wave Z
#define SMEM_FLOATS (SZ_OFF + 16)
#define SMEM_BYTES (SMEM_FLOATS * 4)   // 133,376 B < 160 KiB

__device__ __forceinline__ float sigmoidf_(float v) {
  return 1.0f / (1.0f + __expf(-v));
}

__global__ void __launch_bounds__(THREADS, 4)
capsule_fused(const float* __restrict__ x, const float* __restrict__ w,
              float* __restrict__ out) {
  extern __shared__ float smem[];
  float* Plds = smem;
  float* swv  = smem + SWV_OFF;
  float* sU   = smem + SU_OFF;
  float* sM   = smem + SM_OFF;
  float* sZ   = smem + SZ_OFF;

  const int t    = threadIdx.x;
  const int o4   = t & 7;
  const int G    = t >> 3;
  const int lane = t & 63;
  const int wid  = t >> 6;
  const int swz  = ((o4 ^ (G & 7)) << 2);  // float4 XOR swizzle -> 2-way max

  // XCD-aware mapping: block i lands on XCD i%8; give each XCD 4 k values so
  // w[k] (4 MB) stays resident in that XCD's L2 while its 32 b-blocks stream it.
  const int bid  = blockIdx.x;
  const int xcd  = bid & 7;
  const int slot = bid >> 3;           // 0..127
  const int k    = xcd + 8 * (slot >> 5);
  const int b    = slot & 31;

  const float* __restrict__ xb = x + (size_t)b * (RR * CC);
  const float* __restrict__ wk = w + (size_t)k * ((size_t)RR * CC * OO);

  float4 preg[8];
  float4 cs = make_float4(0.f, 0.f, 0.f, 0.f);

  // ---------------- einsum: build P, accumulate column-sum ----------------
  #pragma unroll
  for (int j = 0; j < 16; ++j) {
    const int r = ((j & 8) ? 1024 : 0) + 8 * G + (j & 7);
    const float* xr = xb + r * CC;
    float xs[16];
    *(float4*)&xs[0]  = *(const float4*)(xr + 0);
    *(float4*)&xs[4]  = *(const float4*)(xr + 4);
    *(float4*)&xs[8]  = *(const float4*)(xr + 8);
    *(float4*)&xs[12] = *(const float4*)(xr + 12);
    const float* wr = wk + (size_t)r * (CC * OO) + (o4 << 2);
    float4 a = make_float4(0.f, 0.f, 0.f, 0.f);
    #pragma unroll
    for (int c = 0; c < CC; ++c) {
      const float4 wv = *(const float4*)(wr + c * OO);
      a.x = fmaf(xs[c], wv.x, a.x);
      a.y = fmaf(xs[c], wv.y, a.y);
      a.z = fmaf(xs[c], wv.z, a.z);
      a.w = fmaf(xs[c], wv.w, a.w);
    }
    if (j < 8) {
      *(float4*)&Plds[((8 * G + (j & 7)) << 5) + swz] = a;
    } else {
      preg[j - 8] = a;
    }
    cs.x += a.x; cs.y += a.y; cs.z += a.z; cs.w += a.w;
  }

  // ---------------- colsum -> u0 ----------------
  // reduce over G: masks 8,16,32 cross the wave's 8 G-groups (same o4)
  #pragma unroll
  for (int m = 8; m <= 32; m <<= 1) {
    cs.x += __shfl_xor(cs.x, m);
    cs.y += __shfl_xor(cs.y, m);
    cs.z += __shfl_xor(cs.z, m);
    cs.w += __shfl_xor(cs.w, m);
  }
  if (lane < 8) *(float4*)&swv[(wid << 5) + (o4 << 2)] = cs;
  __syncthreads();
  if (t < OO) {
    float s = 0.f;
    #pragma unroll
    for (int w2 = 0; w2 < 16; ++w2) s += swv[(w2 << 5) + t];
    sU[t] = sigmoidf_(s * (1.0f / 2048.0f));
  }
  __syncthreads();

  // ---------------- two f(v) passes ----------------
  #pragma unroll 1
  for (int pass = 0; pass < 2; ++pass) {
    const float4 v = *(const float4*)&sU[o4 << 2];

    // d[r] = P[r,:] . v  (partial over own 4 columns, then octet reduce)
    float d[16];
    #pragma unroll
    for (int j = 0; j < 8; ++j) {
      const float4 p = *(const float4*)&Plds[((8 * G + j) << 5) + swz];
      d[j] = p.x * v.x + p.y * v.y + p.z * v.z + p.w * v.w;
    }
    #pragma unroll
    for (int j = 0; j < 8; ++j) {
      const float4 p = preg[j];
      d[8 + j] = p.x * v.x + p.y * v.y + p.z * v.z + p.w * v.w;
    }
    #pragma unroll
    for (int j = 0; j < 16; ++j) {  // masks 1,2,4: sum across o4 octet
      d[j] += __shfl_xor(d[j], 1);
      d[j] += __shfl_xor(d[j], 2);
      d[j] += __shfl_xor(d[j], 4);
    }

    // global max over r
    float mx = d[0];
    #pragma unroll
    for (int j = 1; j < 16; ++j) mx = fmaxf(mx, d[j]);
    mx = fmaxf(mx, __shfl_xor(mx, 8));
    mx = fmaxf(mx, __shfl_xor(mx, 16));
    mx = fmaxf(mx, __shfl_xor(mx, 32));
    if (lane == 0) sM[wid] = mx;
    __syncthreads();
    float M = sM[0];
    #pragma unroll
    for (int w2 = 1; w2 < 16; ++w2) M = fmaxf(M, sM[w2]);

    // exp, Z, and acc[o] = sum_r e[r] * P[r,o]
    float z = 0.f;
    float4 acc = make_float4(0.f, 0.f, 0.f, 0.f);
    #pragma unroll
    for (int j = 0; j < 16; ++j) { d[j] = __expf(d[j] - M); z += d[j]; }
    #pragma unroll
    for (int j = 0; j < 8; ++j) {
      const float4 p = *(const float4*)&Plds[((8 * G + j) << 5) + swz];
      acc.x = fmaf(d[j], p.x, acc.x);
      acc.y = fmaf(d[j], p.y, acc.y);
      acc.z = fmaf(d[j], p.z, acc.z);
      acc.w = fmaf(d[j], p.w, acc.w);
    }
    #pragma unroll
    for (int j = 0; j < 8; ++j) {
      const float4 p = preg[j];
      acc.x = fmaf(d[8 + j], p.x, acc.x);
      acc.y = fmaf(d[8 + j], p.y, acc.y);
      acc.z = fmaf(d[8 + j], p.z, acc.z);
      acc.w = fmaf(d[8 + j], p.w, acc.w);
    }
    #pragma unroll
    for (int m = 8; m <= 32; m <<= 1) {
      z     += __shfl_xor(z, m);
      acc.x += __shfl_xor(acc.x, m);
      acc.y += __shfl_xor(acc.y, m);
      acc.z += __shfl_xor(acc.z, m);
      acc.w += __shfl_xor(acc.w, m);
    }
    if (lane < 8) {
      *(float4*)&swv[(wid << 5) + (o4 << 2)] = acc;
      if (o4 == 0) sZ[wid] = z;
    }
    __syncthreads();
    if (t < OO) {
      float zz = 0.f, s = 0.f;
      #pragma unroll
      for (int w2 = 0; w2 < 16; ++w2) { zz += sZ[w2]; s += swv[(w2 << 5) + t]; }
      const float fo = s / zz;
      if (pass == 0) {
        sU[t] = sU[t] + sigmoidf_(fo);          // v2 = u0 + u1
      } else {
        out[((k << 5) + b) * OO + t] = sigmoidf_(fo);
      }
    }
    __syncthreads();
  }
}

extern "C" void kernel_launch(void* const* d_in, const int* in_sizes, int n_in,
                              void* d_out, int out_size, void* d_ws, size_t ws_size,
                              hipStream_t stream) {
  const float* x = (const float*)d_in[0];
  const float* w = (const float*)d_in[1];
  float* out = (float*)d_out;
  (void)in_sizes; (void)n_in; (void)d_ws; (void)ws_size; (void)out_size;

  hipFuncSetAttribute(reinterpret_cast<const void*>(capsule_fused),
                      hipFuncAttributeMaxDynamicSharedMemorySize, SMEM_BYTES);
  capsule_fused<<<dim3(KK * BB), dim3(THREADS), SMEM_BYTES, stream>>>(x, w, out);
}